// Round 10
// baseline (201.845 us; speedup 1.0000x reference)
//
#include <hip/hip_runtime.h>

#define DIM 256
#define KCAT 512

typedef unsigned short u16;
typedef unsigned int u32;
typedef __bf16 bf16x8 __attribute__((ext_vector_type(8)));
typedef float f32x4 __attribute__((ext_vector_type(4)));

__device__ inline float bf2f(u16 u){ union{u32 i; float f;} v; v.i=((u32)u)<<16; return v.f; }
__device__ inline u16 f2bf(float f){
  union{float f; u32 i;} v; v.f=f;
  u32 i=v.i;
  return (u16)((i + 0x7FFFu + ((i>>16)&1u)) >> 16);  // RNE
}
__device__ inline ushort4 cvt4(float4 v){
  ushort4 r; r.x=f2bf(v.x); r.y=f2bf(v.y); r.z=f2bf(v.z); r.w=f2bf(v.w); return r;
}

// ---- 1: in-degree histogram (int4 edges) ----
__global__ __launch_bounds__(256) void k_hist(const int* __restrict__ dst, int E,
    int* __restrict__ counts){
  int E4 = E >> 2;
  int e = blockIdx.x*256 + threadIdx.x;
  if(e < E4){
    int4 d = ((const int4*)dst)[e];
    atomicAdd(counts + d.x, 1);
    atomicAdd(counts + d.y, 1);
    atomicAdd(counts + d.z, 1);
    atomicAdd(counts + d.w, 1);
  }
  if (e == 0){
    for(int e2 = E4*4; e2 < E; e2++) atomicAdd(counts + dst[e2], 1);
  }
}

// ---- 2: exclusive scan over counts (single block, 20/thread, static regs) ----
__global__ __launch_bounds__(1024) void k_scan(const int* __restrict__ counts, int n,
                                               int* __restrict__ offsets, int* __restrict__ cursor){
  __shared__ int wsum[16];
  int t = threadIdx.x;
  int s0 = t*20;
  int4 c[5];
  int s = 0;
  #pragma unroll
  for(int u=0; u<5; u++){
    int i = s0 + 4*u;
    int4 cv = {0,0,0,0};
    if (i + 3 < n){
      cv = *(const int4*)(counts + i);
    } else {
      if (i   < n) cv.x = counts[i];
      if (i+1 < n) cv.y = counts[i+1];
      if (i+2 < n) cv.z = counts[i+2];
      if (i+3 < n) cv.w = counts[i+3];
    }
    c[u] = cv;
    s += cv.x + cv.y + cv.z + cv.w;
  }
  int lane = t & 63, wid = t >> 6;
  int sc = s;
  #pragma unroll
  for(int off=1; off<64; off<<=1){
    int v = __shfl_up(sc, off, 64);
    if (lane >= off) sc += v;
  }
  if (lane == 63) wsum[wid] = sc;
  __syncthreads();
  if (t == 0){
    int run = 0;
    #pragma unroll
    for(int w=0; w<16; w++){ int v = wsum[w]; wsum[w] = run; run += v; }
  }
  __syncthreads();
  int run = wsum[wid] + (sc - s);
  #pragma unroll
  for(int u=0; u<5; u++){
    int i = s0 + 4*u;
    int4 o;
    o.x = run; run += c[u].x;
    o.y = run; run += c[u].y;
    o.z = run; run += c[u].z;
    o.w = run; run += c[u].w;
    if (i + 3 < n){
      *(int4*)(offsets + i) = o;
      *(int4*)(cursor  + i) = o;
    } else {
      if (i   < n){ offsets[i]   = o.x; cursor[i]   = o.x; }
      if (i+1 < n){ offsets[i+1] = o.y; cursor[i+1] = o.y; }
      if (i+2 < n){ offsets[i+2] = o.z; cursor[i+2] = o.z; }
      if (i+3 < n){ offsets[i+3] = o.w; cursor[i+3] = o.w; }
    }
  }
  if (t == 1023) offsets[n] = wsum[15] + sc;
}

// ---- 3: scatter (int4) + x->bf16 + W->bf16 (overlaps the atomic latency) ----
__global__ __launch_bounds__(256) void k_scatter_cvt(const int* __restrict__ src,
    const int* __restrict__ dst, int E, int* __restrict__ cursor, int* __restrict__ sorted_src,
    const float* __restrict__ x, const float* __restrict__ Wl, const float* __restrict__ Wr,
    u16* __restrict__ xb, u16* __restrict__ Wcat, int nX4, int nW4){
  int E4 = E >> 2;
  int sb = (E4 + 255) >> 8;
  int wb = (2*nW4 + 255) >> 8;
  int b = blockIdx.x, t = threadIdx.x;
  if (b < sb){
    int e = b*256 + t;
    if(e < E4){
      int4 s = ((const int4*)src)[e];
      int4 d = ((const int4*)dst)[e];
      sorted_src[atomicAdd(cursor + d.x, 1)] = s.x;
      sorted_src[atomicAdd(cursor + d.y, 1)] = s.y;
      sorted_src[atomicAdd(cursor + d.z, 1)] = s.z;
      sorted_src[atomicAdd(cursor + d.w, 1)] = s.w;
    }
    if (b==0 && t==0){
      for(int e2 = E4*4; e2 < E; e2++)
        sorted_src[atomicAdd(cursor + dst[e2], 1)] = src[e2];
    }
  } else if (b < sb + wb){
    int i = (b - sb)*256 + t;
    if (i < 2*nW4){
      int sel = (i >= nW4);
      int ii = sel ? i - nW4 : i;
      float4 v = sel ? ((const float4*)Wr)[ii] : ((const float4*)Wl)[ii];
      int col = ii >> 6, k4 = ii & 63;
      ((ushort4*)Wcat)[col*128 + sel*64 + k4] = cvt4(v);
    }
  } else {
    int i = (b - sb - wb)*256 + t;
    if (i < nX4) ((ushort4*)xb)[i] = cvt4(((const float4*)x)[i]);
  }
}

// ---- 4: per-node mean; one wave per node (20000 waves), unroll x8 ----
__global__ __launch_bounds__(256) void k_aggr(const u16* __restrict__ xb,
    const int* __restrict__ offsets, const int* __restrict__ sorted_src,
    u16* __restrict__ aggr, int n_nodes){
  int wave = threadIdx.x >> 6, lane = threadIdx.x & 63;
  int node = blockIdx.x*4 + wave;
  if(node >= n_nodes) return;
  int b0 = offsets[node], b1 = offsets[node+1];
  const u16* xc = xb + lane*4;
  float s0=0.f, s1=0.f, s2=0.f, s3=0.f;
  int i = b0;
  for(; i+8 <= b1; i+=8){
    int idx[8];
    #pragma unroll
    for(int u=0;u<8;u++) idx[u] = sorted_src[i+u];
    ushort4 v[8];
    #pragma unroll
    for(int u=0;u<8;u++) v[u] = *(const ushort4*)(xc + (size_t)idx[u]*DIM);
    #pragma unroll
    for(int u=0;u<8;u++){
      s0 += bf2f(v[u].x); s1 += bf2f(v[u].y); s2 += bf2f(v[u].z); s3 += bf2f(v[u].w);
    }
  }
  for(; i < b1; i++){
    int sn = sorted_src[i];
    ushort4 v = *(const ushort4*)(xc + (size_t)sn*DIM);
    s0 += bf2f(v.x); s1 += bf2f(v.y); s2 += bf2f(v.z); s3 += bf2f(v.w);
  }
  int deg = b1 - b0;
  float inv = 1.0f / (float)(deg > 1 ? deg : 1);
  ushort4 o;
  o.x = f2bf(s0*inv); o.y = f2bf(s1*inv); o.z = f2bf(s2*inv); o.w = f2bf(s3*inv);
  *(ushort4*)(aggr + (size_t)node*DIM + lane*4) = o;
}

// ---- 5: GEMM, occupancy-first streaming design ----
// Wave tile: 16 rows x 32 cols (acc = 2 f32x4 = 8 VGPRs). Per kt: 1 A-load +
// 2 B-loads + 2 MFMAs, 16 kt fully unrolled -> all loads independent.
// __launch_bounds__(256,8): VGPR cap 64 -> 32 waves/CU (100% occupancy).
// Block = 4 waves = 4 col-groups over the same 16 rows; 2 blocks per row-tile.
// Grid = 2500 blocks. B (256 KB) stays L2-resident; A re-read x8 via L2/L3.
// A frag: lane(quad*16+l16) holds A[l16][kt*32+quad*8+j] (16B contiguous)
// D:      lane reg r holds D[quad*4+r][l16]
__global__ __launch_bounds__(256, 8) void k_gemm(const u16* __restrict__ aggr,
    const u16* __restrict__ xb, const u16* __restrict__ Wcat, const float* __restrict__ br,
    float* __restrict__ out, int Mtiles){
  int wid = threadIdx.x >> 6, lane = threadIdx.x & 63;
  int quad = lane >> 4, l16 = lane & 15;
  int half = blockIdx.x & 1;
  int mt   = blockIdx.x >> 1;
  if (mt >= Mtiles) return;
  int colbase = half*128 + wid*32;

  const u16* arowA = aggr + (size_t)(mt*16 + l16)*DIM + quad*8;
  const u16* arowX = xb   + (size_t)(mt*16 + l16)*DIM + quad*8;
  const u16* w0 = Wcat + (size_t)(colbase + l16)*KCAT + quad*8;   // col-tile 0
  const u16* w1 = w0 + (size_t)16*KCAT;                           // col-tile 1

  f32x4 acc0 = {0.f,0.f,0.f,0.f}, acc1 = {0.f,0.f,0.f,0.f};
  #pragma unroll
  for(int kt=0; kt<8; kt++){
    bf16x8 a  = *(const bf16x8*)(arowA + kt*32);
    bf16x8 b0 = *(const bf16x8*)(w0 + kt*32);
    bf16x8 b1 = *(const bf16x8*)(w1 + kt*32);
    acc0 = __builtin_amdgcn_mfma_f32_16x16x32_bf16(a, b0, acc0, 0, 0, 0);
    acc1 = __builtin_amdgcn_mfma_f32_16x16x32_bf16(a, b1, acc1, 0, 0, 0);
  }
  #pragma unroll
  for(int kt=8; kt<16; kt++){
    bf16x8 a  = *(const bf16x8*)(arowX + (kt-8)*32);
    bf16x8 b0 = *(const bf16x8*)(w0 + kt*32);
    bf16x8 b1 = *(const bf16x8*)(w1 + kt*32);
    acc0 = __builtin_amdgcn_mfma_f32_16x16x32_bf16(a, b0, acc0, 0, 0, 0);
    acc1 = __builtin_amdgcn_mfma_f32_16x16x32_bf16(a, b1, acc1, 0, 0, 0);
  }

  int col0 = colbase + l16, col1 = col0 + 16;
  float bi0 = br[col0], bi1 = br[col1];
  size_t base = (size_t)(mt*16 + quad*4)*DIM;
  #pragma unroll
  for(int r=0;r<4;r++){
    out[base + (size_t)r*DIM + col0] = acc0[r] + bi0;
    out[base + (size_t)r*DIM + col1] = acc1[r] + bi1;
  }
}

extern "C" void kernel_launch(void* const* d_in, const int* in_sizes, int n_in,
                              void* d_out, int out_size, void* d_ws, size_t ws_size,
                              hipStream_t stream){
  const float* x  = (const float*)d_in[0];
  const int*   ei = (const int*)d_in[1];
  const float* Wl = (const float*)d_in[2];
  const float* Wr = (const float*)d_in[3];
  const float* br = (const float*)d_in[4];
  float* out = (float*)d_out;
  int n_nodes = in_sizes[0] / DIM;   // 20000
  int E = in_sizes[1] / 2;           // 320000
  const int* src = ei;
  const int* dst = ei + E;

  // workspace layout (16B aligned sections): ~12 MB
  int* counts  = (int*)d_ws;                   // [n]
  int* offsets = counts + n_nodes;             // [n+1] (padded to n+8)
  int* cursor  = offsets + (n_nodes + 8);      // [n]
  int* sorted  = cursor + n_nodes;             // [E]
  u16* xb      = (u16*)(sorted + E);           // [n*DIM] bf16
  u16* aggr    = xb + (size_t)n_nodes*DIM;     // [n*DIM] bf16
  u16* Wcat    = aggr + (size_t)n_nodes*DIM;   // [256*512] bf16: [Wl | Wr] per col

  int nX4 = n_nodes*DIM/4, nW4 = DIM*DIM/4;
  int E4 = E >> 2;
  int scat_blocks = ((E4+255)>>8) + ((2*nW4+255)>>8) + ((nX4+255)>>8);
  int Mtiles = (n_nodes + 15) >> 4;            // 1250

  hipMemsetAsync(counts, 0, (size_t)n_nodes*sizeof(int), stream);
  hipLaunchKernelGGL(k_hist,        dim3((E4+255)/256),  dim3(256), 0, stream,
                     dst, E, counts);
  hipLaunchKernelGGL(k_scan,        dim3(1),             dim3(1024),0, stream,
                     counts, n_nodes, offsets, cursor);
  hipLaunchKernelGGL(k_scatter_cvt, dim3(scat_blocks),   dim3(256), 0, stream,
                     src, dst, E, cursor, sorted, x, Wl, Wr, xb, Wcat, nX4, nW4);
  hipLaunchKernelGGL(k_aggr,        dim3((n_nodes+3)/4), dim3(256), 0, stream,
                     xb, offsets, sorted, aggr, n_nodes);
  hipLaunchKernelGGL(k_gemm,        dim3(Mtiles*2),      dim3(256), 0, stream,
                     aggr, xb, Wcat, br, out, Mtiles);
}

// Round 11
// 167.920 us; speedup vs baseline: 1.2020x; 1.2020x over previous
//
#include <hip/hip_runtime.h>

#define DIM 256
#define KCAT 512
#define BM 128
#define BK 64
#define LSTR 72   // LDS row stride in u16 (64 + 8 pad; 144 B = uniform bank spread, 16B-aligned)

typedef unsigned short u16;
typedef unsigned int u32;
typedef __bf16 bf16x8 __attribute__((ext_vector_type(8)));
typedef float f32x4 __attribute__((ext_vector_type(4)));

__device__ inline float bf2f(u16 u){ union{u32 i; float f;} v; v.i=((u32)u)<<16; return v.f; }
__device__ inline u16 f2bf(float f){
  union{float f; u32 i;} v; v.f=f;
  u32 i=v.i;
  return (u16)((i + 0x7FFFu + ((i>>16)&1u)) >> 16);  // RNE
}
__device__ inline ushort4 cvt4(float4 v){
  ushort4 r; r.x=f2bf(v.x); r.y=f2bf(v.y); r.z=f2bf(v.z); r.w=f2bf(v.w); return r;
}

// ---- 1: in-degree histogram (int4 edges) ----
__global__ __launch_bounds__(256) void k_hist(const int* __restrict__ dst, int E,
    int* __restrict__ counts){
  int E4 = E >> 2;
  int e = blockIdx.x*256 + threadIdx.x;
  if(e < E4){
    int4 d = ((const int4*)dst)[e];
    atomicAdd(counts + d.x, 1);
    atomicAdd(counts + d.y, 1);
    atomicAdd(counts + d.z, 1);
    atomicAdd(counts + d.w, 1);
  }
  if (e == 0){
    for(int e2 = E4*4; e2 < E; e2++) atomicAdd(counts + dst[e2], 1);
  }
}

// ---- 2: exclusive scan over counts (single block, 20/thread, static regs) ----
__global__ __launch_bounds__(1024) void k_scan(const int* __restrict__ counts, int n,
                                               int* __restrict__ offsets, int* __restrict__ cursor){
  __shared__ int wsum[16];
  int t = threadIdx.x;
  int s0 = t*20;
  int4 c[5];
  int s = 0;
  #pragma unroll
  for(int u=0; u<5; u++){
    int i = s0 + 4*u;
    int4 cv = {0,0,0,0};
    if (i + 3 < n){
      cv = *(const int4*)(counts + i);
    } else {
      if (i   < n) cv.x = counts[i];
      if (i+1 < n) cv.y = counts[i+1];
      if (i+2 < n) cv.z = counts[i+2];
      if (i+3 < n) cv.w = counts[i+3];
    }
    c[u] = cv;
    s += cv.x + cv.y + cv.z + cv.w;
  }
  int lane = t & 63, wid = t >> 6;
  int sc = s;
  #pragma unroll
  for(int off=1; off<64; off<<=1){
    int v = __shfl_up(sc, off, 64);
    if (lane >= off) sc += v;
  }
  if (lane == 63) wsum[wid] = sc;
  __syncthreads();
  if (t == 0){
    int run = 0;
    #pragma unroll
    for(int w=0; w<16; w++){ int v = wsum[w]; wsum[w] = run; run += v; }
  }
  __syncthreads();
  int run = wsum[wid] + (sc - s);
  #pragma unroll
  for(int u=0; u<5; u++){
    int i = s0 + 4*u;
    int4 o;
    o.x = run; run += c[u].x;
    o.y = run; run += c[u].y;
    o.z = run; run += c[u].z;
    o.w = run; run += c[u].w;
    if (i + 3 < n){
      *(int4*)(offsets + i) = o;
      *(int4*)(cursor  + i) = o;
    } else {
      if (i   < n){ offsets[i]   = o.x; cursor[i]   = o.x; }
      if (i+1 < n){ offsets[i+1] = o.y; cursor[i+1] = o.y; }
      if (i+2 < n){ offsets[i+2] = o.z; cursor[i+2] = o.z; }
      if (i+3 < n){ offsets[i+3] = o.w; cursor[i+3] = o.w; }
    }
  }
  if (t == 1023) offsets[n] = wsum[15] + sc;
}

// ---- 3: scatter (int4) + x->bf16 + W->bf16 (overlaps the atomic latency) ----
__global__ __launch_bounds__(256) void k_scatter_cvt(const int* __restrict__ src,
    const int* __restrict__ dst, int E, int* __restrict__ cursor, int* __restrict__ sorted_src,
    const float* __restrict__ x, const float* __restrict__ Wl, const float* __restrict__ Wr,
    u16* __restrict__ xb, u16* __restrict__ Wcat, int nX4, int nW4){
  int E4 = E >> 2;
  int sb = (E4 + 255) >> 8;
  int wb = (2*nW4 + 255) >> 8;
  int b = blockIdx.x, t = threadIdx.x;
  if (b < sb){
    int e = b*256 + t;
    if(e < E4){
      int4 s = ((const int4*)src)[e];
      int4 d = ((const int4*)dst)[e];
      sorted_src[atomicAdd(cursor + d.x, 1)] = s.x;
      sorted_src[atomicAdd(cursor + d.y, 1)] = s.y;
      sorted_src[atomicAdd(cursor + d.z, 1)] = s.z;
      sorted_src[atomicAdd(cursor + d.w, 1)] = s.w;
    }
    if (b==0 && t==0){
      for(int e2 = E4*4; e2 < E; e2++)
        sorted_src[atomicAdd(cursor + dst[e2], 1)] = src[e2];
    }
  } else if (b < sb + wb){
    int i = (b - sb)*256 + t;
    if (i < 2*nW4){
      int sel = (i >= nW4);
      int ii = sel ? i - nW4 : i;
      float4 v = sel ? ((const float4*)Wr)[ii] : ((const float4*)Wl)[ii];
      int col = ii >> 6, k4 = ii & 63;
      ((ushort4*)Wcat)[col*128 + sel*64 + k4] = cvt4(v);
    }
  } else {
    int i = (b - sb - wb)*256 + t;
    if (i < nX4) ((ushort4*)xb)[i] = cvt4(((const float4*)x)[i]);
  }
}

// ---- 4: per-node mean; one wave per node (20000 waves), unroll x8 ----
__global__ __launch_bounds__(256) void k_aggr(const u16* __restrict__ xb,
    const int* __restrict__ offsets, const int* __restrict__ sorted_src,
    u16* __restrict__ aggr, int n_nodes){
  int wave = threadIdx.x >> 6, lane = threadIdx.x & 63;
  int node = blockIdx.x*4 + wave;
  if(node >= n_nodes) return;
  int b0 = offsets[node], b1 = offsets[node+1];
  const u16* xc = xb + lane*4;
  float s0=0.f, s1=0.f, s2=0.f, s3=0.f;
  int i = b0;
  for(; i+8 <= b1; i+=8){
    int idx[8];
    #pragma unroll
    for(int u=0;u<8;u++) idx[u] = sorted_src[i+u];
    ushort4 v[8];
    #pragma unroll
    for(int u=0;u<8;u++) v[u] = *(const ushort4*)(xc + (size_t)idx[u]*DIM);
    #pragma unroll
    for(int u=0;u<8;u++){
      s0 += bf2f(v[u].x); s1 += bf2f(v[u].y); s2 += bf2f(v[u].z); s3 += bf2f(v[u].w);
    }
  }
  for(; i < b1; i++){
    int sn = sorted_src[i];
    ushort4 v = *(const ushort4*)(xc + (size_t)sn*DIM);
    s0 += bf2f(v.x); s1 += bf2f(v.y); s2 += bf2f(v.z); s3 += bf2f(v.w);
  }
  int deg = b1 - b0;
  float inv = 1.0f / (float)(deg > 1 ? deg : 1);
  ushort4 o;
  o.x = f2bf(s0*inv); o.y = f2bf(s1*inv); o.z = f2bf(s2*inv); o.w = f2bf(s3*inv);
  *(ushort4*)(aggr + (size_t)node*DIM + lane*4) = o;
}

// ---- 5: LDS-tiled GEMM: out = [aggr|x] @ [Wl|Wr]^T + b ----
// Block tile BM=128 rows x 128 cols, K=512 in 8 chunks of BK=64.
// Staging is fully COALESCED (consecutive threads -> consecutive 16B of a row)
// fixing the 16-cache-line-per-fragment gather of the streaming designs.
// Wave w computes rows [w*32, w*32+32) x all 128 cols: per chunk per wave
// 4 A ds_reads + 16 B ds_reads + 32 MFMAs (each B-frag feeds 2 MFMAs).
// Grid = 314 blocks, all co-resident (36 KB LDS, ~110 VGPR -> >=2 blocks/CU).
// A frag: lane(quad*16+l16) holds A[l16][kt*32+quad*8+j] (16B contiguous)
// D:      lane reg r holds D[quad*4+r][l16]
__global__ __launch_bounds__(256) void k_gemm(const u16* __restrict__ aggr,
    const u16* __restrict__ xb, const u16* __restrict__ Wcat, const float* __restrict__ br,
    float* __restrict__ out, int n_nodes){
  __shared__ u16 At[BM*LSTR];   // 18432 B
  __shared__ u16 Bt[BM*LSTR];   // 18432 B
  int t = threadIdx.x, wid = t >> 6, lane = t & 63;
  int quad = lane >> 4, l16 = lane & 15;
  int half = blockIdx.x & 1;
  int mb   = blockIdx.x >> 1;
  int row0 = mb*BM;

  f32x4 acc0[8], acc1[8];
  #pragma unroll
  for(int i=0;i<8;i++){ f32x4 z = {0.f,0.f,0.f,0.f}; acc0[i]=z; acc1[i]=z; }

  #pragma unroll 1
  for(int kc=0; kc<8; kc++){
    const u16* Asrc = (kc < 4) ? (aggr + kc*BK) : (xb + (kc-4)*BK);
    // stage A chunk: 128 rows x 64 u16 (8 x 16B chunks per row), 4 iters
    #pragma unroll
    for(int it=0; it<4; it++){
      int idx = t + it*256;
      int r = idx >> 3, c = idx & 7;
      int grow = row0 + r; if (grow >= n_nodes) grow = n_nodes - 1;
      uint4 v = *(const uint4*)(Asrc + (size_t)grow*DIM + c*8);
      *(uint4*)(&At[r*LSTR + c*8]) = v;
    }
    // stage B chunk: 128 cols x 64 u16 from Wcat[half*128+col][kc*64 + ...]
    #pragma unroll
    for(int it=0; it<4; it++){
      int idx = t + it*256;
      int col = idx >> 3, c = idx & 7;
      uint4 v = *(const uint4*)(Wcat + (size_t)(half*128 + col)*KCAT + kc*BK + c*8);
      *(uint4*)(&Bt[col*LSTR + c*8]) = v;
    }
    __syncthreads();
    #pragma unroll
    for(int kt=0; kt<2; kt++){
      bf16x8 a0 = *(const bf16x8*)(&At[(wid*32      + l16)*LSTR + kt*32 + quad*8]);
      bf16x8 a1 = *(const bf16x8*)(&At[(wid*32 + 16 + l16)*LSTR + kt*32 + quad*8]);
      #pragma unroll
      for(int ct=0; ct<8; ct++){
        bf16x8 b = *(const bf16x8*)(&Bt[(ct*16 + l16)*LSTR + kt*32 + quad*8]);
        acc0[ct] = __builtin_amdgcn_mfma_f32_16x16x32_bf16(a0, b, acc0[ct], 0, 0, 0);
        acc1[ct] = __builtin_amdgcn_mfma_f32_16x16x32_bf16(a1, b, acc1[ct], 0, 0, 0);
      }
    }
    __syncthreads();
  }

  // epilogue
  int colb = half*128;
  #pragma unroll
  for(int ct=0; ct<8; ct++){
    int col = colb + ct*16 + l16;
    float bi = br[col];
    int r0 = row0 + wid*32 + quad*4;
    #pragma unroll
    for(int r=0;r<4;r++){
      int rowA = r0 + r;
      if (rowA < n_nodes) out[(size_t)rowA*DIM + col] = acc0[ct][r] + bi;
      int rowB = r0 + 16 + r;
      if (rowB < n_nodes) out[(size_t)rowB*DIM + col] = acc1[ct][r] + bi;
    }
  }
}

extern "C" void kernel_launch(void* const* d_in, const int* in_sizes, int n_in,
                              void* d_out, int out_size, void* d_ws, size_t ws_size,
                              hipStream_t stream){
  const float* x  = (const float*)d_in[0];
  const int*   ei = (const int*)d_in[1];
  const float* Wl = (const float*)d_in[2];
  const float* Wr = (const float*)d_in[3];
  const float* br = (const float*)d_in[4];
  float* out = (float*)d_out;
  int n_nodes = in_sizes[0] / DIM;   // 20000
  int E = in_sizes[1] / 2;           // 320000
  const int* src = ei;
  const int* dst = ei + E;

  // workspace layout (16B aligned sections): ~12 MB
  int* counts  = (int*)d_ws;                   // [n]
  int* offsets = counts + n_nodes;             // [n+1] (padded to n+8)
  int* cursor  = offsets + (n_nodes + 8);      // [n]
  int* sorted  = cursor + n_nodes;             // [E]
  u16* xb      = (u16*)(sorted + E);           // [n*DIM] bf16
  u16* aggr    = xb + (size_t)n_nodes*DIM;     // [n*DIM] bf16
  u16* Wcat    = aggr + (size_t)n_nodes*DIM;   // [256*512] bf16: [Wl | Wr] per col

  int nX4 = n_nodes*DIM/4, nW4 = DIM*DIM/4;
  int E4 = E >> 2;
  int scat_blocks = ((E4+255)>>8) + ((2*nW4+255)>>8) + ((nX4+255)>>8);
  int mtiles = (n_nodes + BM - 1) / BM;        // 157
  int gemm_blocks = mtiles*2;                  // 314

  hipMemsetAsync(counts, 0, (size_t)n_nodes*sizeof(int), stream);
  hipLaunchKernelGGL(k_hist,        dim3((E4+255)/256),  dim3(256), 0, stream,
                     dst, E, counts);
  hipLaunchKernelGGL(k_scan,        dim3(1),             dim3(1024),0, stream,
                     counts, n_nodes, offsets, cursor);
  hipLaunchKernelGGL(k_scatter_cvt, dim3(scat_blocks),   dim3(256), 0, stream,
                     src, dst, E, cursor, sorted, x, Wl, Wr, xb, Wcat, nX4, nW4);
  hipLaunchKernelGGL(k_aggr,        dim3((n_nodes+3)/4), dim3(256), 0, stream,
                     xb, offsets, sorted, aggr, n_nodes);
  hipLaunchKernelGGL(k_gemm,        dim3(gemm_blocks),   dim3(256), 0, stream,
                     aggr, xb, Wcat, br, out, n_nodes);
}